// Round 4
// baseline (1437.743 us; speedup 1.0000x reference)
//
#include <hip/hip_runtime.h>
#include <math.h>

// ---------------------------------------------------------------------------
// VQ-VAE 3D forward, round 4.
// Round-3 diagnosis: VGPR_Count=36 on kernels with >=59 live floats => the
// compiler parked accumulators in AGPRs (v_accvgpr_read/write around every
// fma = ~3x VALU inflation; measured VALU-busy 218us vs 55us FMA floor on
// convT2). Fix: __launch_bounds__(256, 4) => 128-VGPR budget, accs stay in
// arch VGPRs. Also: convT3 moved off the LDS-bound tile kernel onto the
// octet-per-thread template (SGPR weights, 64 FMA per 9 loads per ci).
// ---------------------------------------------------------------------------

__device__ __forceinline__ float4 ld4(const float* p) {
  float4 q; __builtin_memcpy(&q, p, 16); return q;
}
struct F3 { float x, y, z; };
__device__ __forceinline__ F3 ld3(const float* p) {
  F3 q; __builtin_memcpy(&q, p, 12); return q;
}

// ---------------- halo zeroing for padded buffers ---------------------------
template<int S, int D, int NCH>
__global__ __launch_bounds__(256) void k_zhalo(float* __restrict__ buf) {
  const int vol = S * S * S;
  const long long idx = (long long)blockIdx.x * 256 + threadIdx.x;
  if (idx >= (long long)NCH * vol) return;
  const int r = (int)(idx % vol);
  const int z = r / (S * S), y = (r / S) % S, x = r % S;
  if (z < 1 || z > D || y < 1 || y > D || x < 1 || x > D) buf[idx] = 0.0f;
}

// ---------------- forward conv (k=4,s=2,p=1) --------------------------------
// xin: [B,CIN,*] (padded stride SIN if INP else dense DIN), wg: OIDHW,
// out: [B,COUT,*] (padded SOUT if OUTP else dense DOUT).
// block 256 = 8x8x4 outputs, OCG channels per block (grid.y).
template<int CIN, int COUT, int DIN, int DOUT, int OCG, bool RELU,
         bool INP, int SIN, bool OUTP, int SOUT>
__global__ __launch_bounds__(256, 4) void k_conv(const float* __restrict__ xin,
                                                 const float* __restrict__ wg,
                                                 const float* __restrict__ bias,
                                                 float* __restrict__ out) {
  constexpr int NBX = DOUT / 8, NBY = DOUT / 8, NBZ = DOUT / 4;
  constexpr size_t VIN  = INP  ? (size_t)SIN * SIN * SIN : (size_t)DIN * DIN * DIN;
  constexpr size_t VOUT = OUTP ? (size_t)SOUT * SOUT * SOUT : (size_t)DOUT * DOUT * DOUT;
  const int tid = threadIdx.x;
  const int tx = tid & 7, ty = (tid >> 3) & 7, tz = tid >> 6;
  int bb = blockIdx.x;
  const int gx = bb % NBX; bb /= NBX;
  const int gy = bb % NBY; bb /= NBY;
  const int gz = bb % NBZ; bb /= NBZ;
  const int b = bb;
  const int oc0 = blockIdx.y * OCG;
  const int ow = gx * 8 + tx, oh = gy * 8 + ty, od = gz * 4 + tz;
  const int iw0 = ow * 2 - 1, ih0 = oh * 2 - 1, id0 = od * 2 - 1;

  float acc[OCG];
#pragma unroll
  for (int c = 0; c < OCG; ++c) acc[c] = 0.0f;

#pragma unroll 1
  for (int ci = 0; ci < CIN; ++ci) {
    const float* xb = xin + (size_t)(b * CIN + ci) * VIN;
    const float* wb = wg + ((size_t)oc0 * CIN + ci) * 64;
#pragma unroll 1
    for (int kd = 0; kd < 4; ++kd) {
      float4 q[4];
      if (INP) {
        const float* rowb = xb + ((size_t)(id0 + kd + 1) * SIN + (ih0 + 1)) * SIN
                               + (iw0 + 1);
#pragma unroll
        for (int kh = 0; kh < 4; ++kh) q[kh] = ld4(rowb + (size_t)kh * SIN);
      } else {
        const int id = id0 + kd;
        const bool vd = (unsigned)id < (unsigned)DIN;
#pragma unroll
        for (int kh = 0; kh < 4; ++kh) {
          const int ih = ih0 + kh;
          const bool vh = vd && ((unsigned)ih < (unsigned)DIN);
          const float* xr = xb + ((size_t)id * DIN + ih) * DIN + iw0;
          float t0 = (vh && ((unsigned)(iw0 + 0) < (unsigned)DIN)) ? xr[0] : 0.0f;
          float t1 = (vh && ((unsigned)(iw0 + 1) < (unsigned)DIN)) ? xr[1] : 0.0f;
          float t2 = (vh && ((unsigned)(iw0 + 2) < (unsigned)DIN)) ? xr[2] : 0.0f;
          float t3 = (vh && ((unsigned)(iw0 + 3) < (unsigned)DIN)) ? xr[3] : 0.0f;
          q[kh] = make_float4(t0, t1, t2, t3);
        }
      }
#pragma unroll
      for (int c = 0; c < OCG; ++c) {
        const float* wr = wb + (size_t)c * (CIN * 64) + kd * 16;  // uniform -> s_load
        acc[c] = fmaf(q[0].x, wr[0],  acc[c]);
        acc[c] = fmaf(q[0].y, wr[1],  acc[c]);
        acc[c] = fmaf(q[0].z, wr[2],  acc[c]);
        acc[c] = fmaf(q[0].w, wr[3],  acc[c]);
        acc[c] = fmaf(q[1].x, wr[4],  acc[c]);
        acc[c] = fmaf(q[1].y, wr[5],  acc[c]);
        acc[c] = fmaf(q[1].z, wr[6],  acc[c]);
        acc[c] = fmaf(q[1].w, wr[7],  acc[c]);
        acc[c] = fmaf(q[2].x, wr[8],  acc[c]);
        acc[c] = fmaf(q[2].y, wr[9],  acc[c]);
        acc[c] = fmaf(q[2].z, wr[10], acc[c]);
        acc[c] = fmaf(q[2].w, wr[11], acc[c]);
        acc[c] = fmaf(q[3].x, wr[12], acc[c]);
        acc[c] = fmaf(q[3].y, wr[13], acc[c]);
        acc[c] = fmaf(q[3].z, wr[14], acc[c]);
        acc[c] = fmaf(q[3].w, wr[15], acc[c]);
      }
    }
  }

#pragma unroll
  for (int c = 0; c < OCG; ++c) {
    float v = acc[c] + bias[oc0 + c];
    if (RELU) v = fmaxf(v, 0.0f);
    if (OUTP)
      out[(size_t)(b * COUT + oc0 + c) * VOUT
          + ((size_t)(od + 1) * SOUT + (oh + 1)) * SOUT + (ow + 1)] = v;
    else
      out[(size_t)(b * COUT + oc0 + c) * VOUT
          + ((size_t)od * DOUT + oh) * DOUT + ow] = v;
  }
}

// ---------------- transposed conv (k=4,s=2,p=1), octet-per-thread -----------
// Input padded (stride SIN, +1 offset). Output padded (SOUT) or dense (2*DIN).
// EPI: 0 = none, 1 = relu, 2 = sigmoid.
// Thread owns the 2x2x2 output octet of m-cube; tap indices are thread-uniform
// so weights come via s_load; 27-point x neighborhood register-cached.
template<int CIN, int COUT, int DIN, int OCG, int EPI, int SIN,
         bool OUTP, int SOUT>
__global__ __launch_bounds__(256, 4) void k_convt(const float* __restrict__ xin,
                                                  const float* __restrict__ wg,
                                                  const float* __restrict__ bias,
                                                  float* __restrict__ out) {
  constexpr int DOUT = 2 * DIN;
  constexpr int NBX = DIN / 8, NBY = DIN / 8, NBZ = DIN / 4;
  constexpr size_t VIN  = (size_t)SIN * SIN * SIN;
  constexpr size_t VOUT = OUTP ? (size_t)SOUT * SOUT * SOUT
                               : (size_t)DOUT * DOUT * DOUT;
  const int tid = threadIdx.x;
  const int tx = tid & 7, ty = (tid >> 3) & 7, tz = tid >> 6;
  int bb = blockIdx.x;
  const int gx = bb % NBX; bb /= NBX;
  const int gy = bb % NBY; bb /= NBY;
  const int gz = bb % NBZ; bb /= NBZ;
  const int b = bb;
  const int oc0 = blockIdx.y * OCG;
  const int mx = gx * 8 + tx, my = gy * 8 + ty, mz = gz * 4 + tz;

  float acc[8][OCG];
#pragma unroll
  for (int p = 0; p < 8; ++p)
#pragma unroll
    for (int c = 0; c < OCG; ++c) acc[p][c] = 0.0f;

#pragma unroll 1
  for (int ci = 0; ci < CIN; ++ci) {
    const float* xb = xin + (size_t)(b * CIN + ci) * VIN
                          + ((size_t)mz * SIN + my) * SIN + mx;
    float xn[27];
#pragma unroll
    for (int dz = 0; dz < 3; ++dz)
#pragma unroll
      for (int dy = 0; dy < 3; ++dy) {
        F3 t = ld3(xb + ((size_t)dz * SIN + dy) * SIN);
        xn[(dz * 3 + dy) * 3 + 0] = t.x;
        xn[(dz * 3 + dy) * 3 + 1] = t.y;
        xn[(dz * 3 + dy) * 3 + 2] = t.z;
      }
#pragma unroll
    for (int c = 0; c < OCG; ++c) {
      const float* wc = wg + ((size_t)ci * COUT + oc0 + c) * 64;  // uniform
#pragma unroll
      for (int p = 0; p < 8; ++p) {
        const int pz = p >> 2, py = (p >> 1) & 1, px = p & 1;
#pragma unroll
        for (int az = 0; az < 2; ++az) {
          const int dz = pz + az, kz = 3 - 2 * dz + pz;
#pragma unroll
          for (int ay = 0; ay < 2; ++ay) {
            const int dy = py + ay, ky = 3 - 2 * dy + py;
#pragma unroll
            for (int ax = 0; ax < 2; ++ax) {
              const int dx = px + ax, kx = 3 - 2 * dx + px;
              acc[p][c] = fmaf(xn[(dz * 3 + dy) * 3 + dx],
                               wc[(kz * 4 + ky) * 4 + kx], acc[p][c]);
            }
          }
        }
      }
    }
  }

#pragma unroll
  for (int c = 0; c < OCG; ++c) {
    const float bv = bias[oc0 + c];
#pragma unroll
    for (int p = 0; p < 8; ++p) {
      const int pz = p >> 2, py = (p >> 1) & 1, px = p & 1;
      float v = acc[p][c] + bv;
      if (EPI == 1) v = fmaxf(v, 0.0f);
      if (EPI == 2) v = 1.0f / (1.0f + expf(-v));
      if (OUTP)
        out[(size_t)(b * COUT + oc0 + c) * VOUT
            + ((size_t)(2 * mz + pz + 1) * SOUT + (2 * my + py + 1)) * SOUT
            + (2 * mx + px + 1)] = v;
      else
        out[(size_t)(b * COUT + oc0 + c) * VOUT
            + ((size_t)(2 * mz + pz) * DOUT + (2 * my + py)) * DOUT
            + (2 * mx + px)] = v;
    }
  }
}

// ---------------- VQ: argmin over 512 codes, gather codebook ----------------
__global__ __launch_bounds__(256) void k_vq(const float* __restrict__ ze,
                                            const float* __restrict__ cb,
                                            float* __restrict__ quant,
                                            float* __restrict__ quantp) {
  __shared__ float ct[64 * 65];
  __shared__ float zs[4][64];
  __shared__ int   bis[4];
  const int tid  = threadIdx.x;
  const int lane = tid & 63;
  const int wv   = tid >> 6;
  const int p0 = blockIdx.x * 4;
  const int b  = p0 >> 12;
  const int n0 = p0 & 4095;

  {
    const int c = tid >> 2, j = tid & 3;
    zs[j][c] = ze[((size_t)(b * 64 + c) << 12) + n0 + j];
  }

  float best = 3.4e38f;
  int bi = 0;
#pragma unroll 1
  for (int ch = 0; ch < 8; ++ch) {
    __syncthreads();
    for (int i = tid; i < 4096; i += 256) {
      const int r = i >> 6, c = i & 63;
      ct[r * 65 + c] = cb[((ch * 64 + r) << 6) + c];
    }
    __syncthreads();
    float d = 0.0f;
#pragma unroll 8
    for (int c = 0; c < 64; ++c) {
      const float t = zs[wv][c] - ct[lane * 65 + c];
      d = fmaf(t, t, d);
    }
    const int k = ch * 64 + lane;
    if (d < best) { best = d; bi = k; }
  }
#pragma unroll
  for (int off = 32; off > 0; off >>= 1) {
    const float ob = __shfl_down(best, off);
    const int   oi = __shfl_down(bi, off);
    if (ob < best || (ob == best && oi < bi)) { best = ob; bi = oi; }
  }
  if (lane == 0) bis[wv] = bi;
  __syncthreads();
  {
    const int c = tid >> 2, j = tid & 3;
    const float val = cb[(bis[j] << 6) + c];
    const int n = n0 + j;
    quant[((size_t)(b * 64 + c) << 12) + n] = val;
    const int zz = n >> 8, yy = (n >> 4) & 15, xx = n & 15;
    quantp[(size_t)(b * 64 + c) * 8000
           + ((size_t)(zz + 1) * 20 + (yy + 1)) * 20 + (xx + 1)] = val;
  }
}

// ---------------------------------------------------------------------------
extern "C" void kernel_launch(void* const* d_in, const int* in_sizes, int n_in,
                              void* d_out, int out_size, void* d_ws, size_t ws_size,
                              hipStream_t stream) {
  const float* x   = (const float*)d_in[0];
  const float* w1  = (const float*)d_in[1];
  const float* b1  = (const float*)d_in[2];
  const float* w2  = (const float*)d_in[3];
  const float* b2  = (const float*)d_in[4];
  const float* w3  = (const float*)d_in[5];
  const float* b3  = (const float*)d_in[6];
  const float* cb  = (const float*)d_in[7];
  const float* dw1 = (const float*)d_in[8];
  const float* db1 = (const float*)d_in[9];
  const float* dw2 = (const float*)d_in[10];
  const float* db2 = (const float*)d_in[11];
  const float* dw3 = (const float*)d_in[12];
  const float* db3 = (const float*)d_in[13];

  float* outf  = (float*)d_out;
  float* xhat  = outf;               // [4,1,128^3]
  float* quant = outf + 8388608;     // [4,64,16^3]
  float* ze    = outf + 9437184;     // [4,64,16^3]

  // padded workspace regions:
  //  regA: 64 ch-vols x 68^3  (y1, then d2)
  //  regB: 128 ch-vols x 36^3 (y2, then d1)
  //  regC: 256 ch-vols x 20^3 (quantp)
  float* regA = (float*)d_ws;
  float* regB = regA + (size_t)64 * 68 * 68 * 68;
  float* regC = regB + (size_t)128 * 36 * 36 * 36;

  // zero halos (ws is re-poisoned before every launch)
  k_zhalo<68, 64, 64><<<78608, 256, 0, stream>>>(regA);
  k_zhalo<36, 32, 128><<<23328, 256, 0, stream>>>(regB);
  k_zhalo<20, 16, 256><<<8000, 256, 0, stream>>>(regC);

  // encoder
  k_conv<1, 16, 128, 64, 16, true, false, 0, true, 68>
      <<<dim3(4096, 1), 256, 0, stream>>>(x, w1, b1, regA);
  k_conv<16, 32, 64, 32, 16, true, true, 68, true, 36>
      <<<dim3(512, 2), 256, 0, stream>>>(regA, w2, b2, regB);
  k_conv<32, 64, 32, 16, 4, false, true, 36, false, 16>
      <<<dim3(64, 16), 256, 0, stream>>>(regB, w3, b3, ze);
  // vector quantization
  k_vq<<<4096, 256, 0, stream>>>(ze, cb, quant, regC);
  // decoder
  k_convt<64, 32, 16, 2, 1, 20, true, 36>
      <<<dim3(64, 16), 256, 0, stream>>>(regC, dw1, db1, regB);
  k_convt<32, 16, 32, 4, 1, 36, true, 68>
      <<<dim3(512, 4), 256, 0, stream>>>(regB, dw2, db2, regA);
  k_convt<16, 1, 64, 1, 2, 68, false, 0>
      <<<dim3(4096, 1), 256, 0, stream>>>(regA, dw3, db3, xhat);
}

// Round 5
// 1337.348 us; speedup vs baseline: 1.0751x; 1.0751x over previous
//
#include <hip/hip_runtime.h>
#include <math.h>

// ---------------------------------------------------------------------------
// VQ-VAE 3D forward, round 5.
// Round-4 falsified "__launch_bounds__(256,4) frees registers": VGPR_Count
// DROPPED to 24 (the 2nd arg is a MIN-waves constraint -> allocator starved
// harder, arch 24 + AGPR-shuffle ~= 64-reg/8-wave target; VALU stream ~4x the
// FMA floor on conv2: 218us busy vs 55us floor). This round: single variable —
// __attribute__((amdgpu_waves_per_eu(2,4))) on all heavy kernels: min=2 waves
// grants a 256-VGPR budget, max=4 stops the allocator from chasing 8 waves.
// Everything else identical to round 4.
// ---------------------------------------------------------------------------

__device__ __forceinline__ float4 ld4(const float* p) {
  float4 q; __builtin_memcpy(&q, p, 16); return q;
}
struct F3 { float x, y, z; };
__device__ __forceinline__ F3 ld3(const float* p) {
  F3 q; __builtin_memcpy(&q, p, 12); return q;
}

#define WAVES_HINT __attribute__((amdgpu_waves_per_eu(2, 4)))

// ---------------- halo zeroing for padded buffers ---------------------------
template<int S, int D, int NCH>
__global__ __launch_bounds__(256) void k_zhalo(float* __restrict__ buf) {
  const int vol = S * S * S;
  const long long idx = (long long)blockIdx.x * 256 + threadIdx.x;
  if (idx >= (long long)NCH * vol) return;
  const int r = (int)(idx % vol);
  const int z = r / (S * S), y = (r / S) % S, x = r % S;
  if (z < 1 || z > D || y < 1 || y > D || x < 1 || x > D) buf[idx] = 0.0f;
}

// ---------------- forward conv (k=4,s=2,p=1) --------------------------------
// xin: [B,CIN,*] (padded stride SIN if INP else dense DIN), wg: OIDHW,
// out: [B,COUT,*] (padded SOUT if OUTP else dense DOUT).
// block 256 = 8x8x4 outputs, OCG channels per block (grid.y).
template<int CIN, int COUT, int DIN, int DOUT, int OCG, bool RELU,
         bool INP, int SIN, bool OUTP, int SOUT>
__global__ __launch_bounds__(256) WAVES_HINT
void k_conv(const float* __restrict__ xin,
            const float* __restrict__ wg,
            const float* __restrict__ bias,
            float* __restrict__ out) {
  constexpr int NBX = DOUT / 8, NBY = DOUT / 8, NBZ = DOUT / 4;
  constexpr size_t VIN  = INP  ? (size_t)SIN * SIN * SIN : (size_t)DIN * DIN * DIN;
  constexpr size_t VOUT = OUTP ? (size_t)SOUT * SOUT * SOUT : (size_t)DOUT * DOUT * DOUT;
  const int tid = threadIdx.x;
  const int tx = tid & 7, ty = (tid >> 3) & 7, tz = tid >> 6;
  int bb = blockIdx.x;
  const int gx = bb % NBX; bb /= NBX;
  const int gy = bb % NBY; bb /= NBY;
  const int gz = bb % NBZ; bb /= NBZ;
  const int b = bb;
  const int oc0 = blockIdx.y * OCG;
  const int ow = gx * 8 + tx, oh = gy * 8 + ty, od = gz * 4 + tz;
  const int iw0 = ow * 2 - 1, ih0 = oh * 2 - 1, id0 = od * 2 - 1;

  float acc[OCG];
#pragma unroll
  for (int c = 0; c < OCG; ++c) acc[c] = 0.0f;

#pragma unroll 1
  for (int ci = 0; ci < CIN; ++ci) {
    const float* xb = xin + (size_t)(b * CIN + ci) * VIN;
    const float* wb = wg + ((size_t)oc0 * CIN + ci) * 64;
#pragma unroll 1
    for (int kd = 0; kd < 4; ++kd) {
      float4 q[4];
      if (INP) {
        const float* rowb = xb + ((size_t)(id0 + kd + 1) * SIN + (ih0 + 1)) * SIN
                               + (iw0 + 1);
#pragma unroll
        for (int kh = 0; kh < 4; ++kh) q[kh] = ld4(rowb + (size_t)kh * SIN);
      } else {
        const int id = id0 + kd;
        const bool vd = (unsigned)id < (unsigned)DIN;
#pragma unroll
        for (int kh = 0; kh < 4; ++kh) {
          const int ih = ih0 + kh;
          const bool vh = vd && ((unsigned)ih < (unsigned)DIN);
          const float* xr = xb + ((size_t)id * DIN + ih) * DIN + iw0;
          float t0 = (vh && ((unsigned)(iw0 + 0) < (unsigned)DIN)) ? xr[0] : 0.0f;
          float t1 = (vh && ((unsigned)(iw0 + 1) < (unsigned)DIN)) ? xr[1] : 0.0f;
          float t2 = (vh && ((unsigned)(iw0 + 2) < (unsigned)DIN)) ? xr[2] : 0.0f;
          float t3 = (vh && ((unsigned)(iw0 + 3) < (unsigned)DIN)) ? xr[3] : 0.0f;
          q[kh] = make_float4(t0, t1, t2, t3);
        }
      }
#pragma unroll
      for (int c = 0; c < OCG; ++c) {
        const float* wr = wb + (size_t)c * (CIN * 64) + kd * 16;  // uniform -> s_load
        acc[c] = fmaf(q[0].x, wr[0],  acc[c]);
        acc[c] = fmaf(q[0].y, wr[1],  acc[c]);
        acc[c] = fmaf(q[0].z, wr[2],  acc[c]);
        acc[c] = fmaf(q[0].w, wr[3],  acc[c]);
        acc[c] = fmaf(q[1].x, wr[4],  acc[c]);
        acc[c] = fmaf(q[1].y, wr[5],  acc[c]);
        acc[c] = fmaf(q[1].z, wr[6],  acc[c]);
        acc[c] = fmaf(q[1].w, wr[7],  acc[c]);
        acc[c] = fmaf(q[2].x, wr[8],  acc[c]);
        acc[c] = fmaf(q[2].y, wr[9],  acc[c]);
        acc[c] = fmaf(q[2].z, wr[10], acc[c]);
        acc[c] = fmaf(q[2].w, wr[11], acc[c]);
        acc[c] = fmaf(q[3].x, wr[12], acc[c]);
        acc[c] = fmaf(q[3].y, wr[13], acc[c]);
        acc[c] = fmaf(q[3].z, wr[14], acc[c]);
        acc[c] = fmaf(q[3].w, wr[15], acc[c]);
      }
    }
  }

#pragma unroll
  for (int c = 0; c < OCG; ++c) {
    float v = acc[c] + bias[oc0 + c];
    if (RELU) v = fmaxf(v, 0.0f);
    if (OUTP)
      out[(size_t)(b * COUT + oc0 + c) * VOUT
          + ((size_t)(od + 1) * SOUT + (oh + 1)) * SOUT + (ow + 1)] = v;
    else
      out[(size_t)(b * COUT + oc0 + c) * VOUT
          + ((size_t)od * DOUT + oh) * DOUT + ow] = v;
  }
}

// ---------------- transposed conv (k=4,s=2,p=1), octet-per-thread -----------
// Input padded (stride SIN, +1 offset). Output padded (SOUT) or dense (2*DIN).
// EPI: 0 = none, 1 = relu, 2 = sigmoid.
template<int CIN, int COUT, int DIN, int OCG, int EPI, int SIN,
         bool OUTP, int SOUT>
__global__ __launch_bounds__(256) WAVES_HINT
void k_convt(const float* __restrict__ xin,
             const float* __restrict__ wg,
             const float* __restrict__ bias,
             float* __restrict__ out) {
  constexpr int DOUT = 2 * DIN;
  constexpr int NBX = DIN / 8, NBY = DIN / 8, NBZ = DIN / 4;
  constexpr size_t VIN  = (size_t)SIN * SIN * SIN;
  constexpr size_t VOUT = OUTP ? (size_t)SOUT * SOUT * SOUT
                               : (size_t)DOUT * DOUT * DOUT;
  const int tid = threadIdx.x;
  const int tx = tid & 7, ty = (tid >> 3) & 7, tz = tid >> 6;
  int bb = blockIdx.x;
  const int gx = bb % NBX; bb /= NBX;
  const int gy = bb % NBY; bb /= NBY;
  const int gz = bb % NBZ; bb /= NBZ;
  const int b = bb;
  const int oc0 = blockIdx.y * OCG;
  const int mx = gx * 8 + tx, my = gy * 8 + ty, mz = gz * 4 + tz;

  float acc[8][OCG];
#pragma unroll
  for (int p = 0; p < 8; ++p)
#pragma unroll
    for (int c = 0; c < OCG; ++c) acc[p][c] = 0.0f;

#pragma unroll 1
  for (int ci = 0; ci < CIN; ++ci) {
    const float* xb = xin + (size_t)(b * CIN + ci) * VIN
                          + ((size_t)mz * SIN + my) * SIN + mx;
    float xn[27];
#pragma unroll
    for (int dz = 0; dz < 3; ++dz)
#pragma unroll
      for (int dy = 0; dy < 3; ++dy) {
        F3 t = ld3(xb + ((size_t)dz * SIN + dy) * SIN);
        xn[(dz * 3 + dy) * 3 + 0] = t.x;
        xn[(dz * 3 + dy) * 3 + 1] = t.y;
        xn[(dz * 3 + dy) * 3 + 2] = t.z;
      }
#pragma unroll
    for (int c = 0; c < OCG; ++c) {
      const float* wc = wg + ((size_t)ci * COUT + oc0 + c) * 64;  // uniform
#pragma unroll
      for (int p = 0; p < 8; ++p) {
        const int pz = p >> 2, py = (p >> 1) & 1, px = p & 1;
#pragma unroll
        for (int az = 0; az < 2; ++az) {
          const int dz = pz + az, kz = 3 - 2 * dz + pz;
#pragma unroll
          for (int ay = 0; ay < 2; ++ay) {
            const int dy = py + ay, ky = 3 - 2 * dy + py;
#pragma unroll
            for (int ax = 0; ax < 2; ++ax) {
              const int dx = px + ax, kx = 3 - 2 * dx + px;
              acc[p][c] = fmaf(xn[(dz * 3 + dy) * 3 + dx],
                               wc[(kz * 4 + ky) * 4 + kx], acc[p][c]);
            }
          }
        }
      }
    }
  }

#pragma unroll
  for (int c = 0; c < OCG; ++c) {
    const float bv = bias[oc0 + c];
#pragma unroll
    for (int p = 0; p < 8; ++p) {
      const int pz = p >> 2, py = (p >> 1) & 1, px = p & 1;
      float v = acc[p][c] + bv;
      if (EPI == 1) v = fmaxf(v, 0.0f);
      if (EPI == 2) v = 1.0f / (1.0f + expf(-v));
      if (OUTP)
        out[(size_t)(b * COUT + oc0 + c) * VOUT
            + ((size_t)(2 * mz + pz + 1) * SOUT + (2 * my + py + 1)) * SOUT
            + (2 * mx + px + 1)] = v;
      else
        out[(size_t)(b * COUT + oc0 + c) * VOUT
            + ((size_t)(2 * mz + pz) * DOUT + (2 * my + py)) * DOUT
            + (2 * mx + px)] = v;
    }
  }
}

// ---------------- VQ: argmin over 512 codes, gather codebook ----------------
__global__ __launch_bounds__(256) void k_vq(const float* __restrict__ ze,
                                            const float* __restrict__ cb,
                                            float* __restrict__ quant,
                                            float* __restrict__ quantp) {
  __shared__ float ct[64 * 65];
  __shared__ float zs[4][64];
  __shared__ int   bis[4];
  const int tid  = threadIdx.x;
  const int lane = tid & 63;
  const int wv   = tid >> 6;
  const int p0 = blockIdx.x * 4;
  const int b  = p0 >> 12;
  const int n0 = p0 & 4095;

  {
    const int c = tid >> 2, j = tid & 3;
    zs[j][c] = ze[((size_t)(b * 64 + c) << 12) + n0 + j];
  }

  float best = 3.4e38f;
  int bi = 0;
#pragma unroll 1
  for (int ch = 0; ch < 8; ++ch) {
    __syncthreads();
    for (int i = tid; i < 4096; i += 256) {
      const int r = i >> 6, c = i & 63;
      ct[r * 65 + c] = cb[((ch * 64 + r) << 6) + c];
    }
    __syncthreads();
    float d = 0.0f;
#pragma unroll 8
    for (int c = 0; c < 64; ++c) {
      const float t = zs[wv][c] - ct[lane * 65 + c];
      d = fmaf(t, t, d);
    }
    const int k = ch * 64 + lane;
    if (d < best) { best = d; bi = k; }
  }
#pragma unroll
  for (int off = 32; off > 0; off >>= 1) {
    const float ob = __shfl_down(best, off);
    const int   oi = __shfl_down(bi, off);
    if (ob < best || (ob == best && oi < bi)) { best = ob; bi = oi; }
  }
  if (lane == 0) bis[wv] = bi;
  __syncthreads();
  {
    const int c = tid >> 2, j = tid & 3;
    const float val = cb[(bis[j] << 6) + c];
    const int n = n0 + j;
    quant[((size_t)(b * 64 + c) << 12) + n] = val;
    const int zz = n >> 8, yy = (n >> 4) & 15, xx = n & 15;
    quantp[(size_t)(b * 64 + c) * 8000
           + ((size_t)(zz + 1) * 20 + (yy + 1)) * 20 + (xx + 1)] = val;
  }
}

// ---------------------------------------------------------------------------
extern "C" void kernel_launch(void* const* d_in, const int* in_sizes, int n_in,
                              void* d_out, int out_size, void* d_ws, size_t ws_size,
                              hipStream_t stream) {
  const float* x   = (const float*)d_in[0];
  const float* w1  = (const float*)d_in[1];
  const float* b1  = (const float*)d_in[2];
  const float* w2  = (const float*)d_in[3];
  const float* b2  = (const float*)d_in[4];
  const float* w3  = (const float*)d_in[5];
  const float* b3  = (const float*)d_in[6];
  const float* cb  = (const float*)d_in[7];
  const float* dw1 = (const float*)d_in[8];
  const float* db1 = (const float*)d_in[9];
  const float* dw2 = (const float*)d_in[10];
  const float* db2 = (const float*)d_in[11];
  const float* dw3 = (const float*)d_in[12];
  const float* db3 = (const float*)d_in[13];

  float* outf  = (float*)d_out;
  float* xhat  = outf;               // [4,1,128^3]
  float* quant = outf + 8388608;     // [4,64,16^3]
  float* ze    = outf + 9437184;     // [4,64,16^3]

  // padded workspace regions:
  //  regA: 64 ch-vols x 68^3  (y1, then d2)
  //  regB: 128 ch-vols x 36^3 (y2, then d1)
  //  regC: 256 ch-vols x 20^3 (quantp)
  float* regA = (float*)d_ws;
  float* regB = regA + (size_t)64 * 68 * 68 * 68;
  float* regC = regB + (size_t)128 * 36 * 36 * 36;

  // zero halos (ws is re-poisoned before every launch)
  k_zhalo<68, 64, 64><<<78608, 256, 0, stream>>>(regA);
  k_zhalo<36, 32, 128><<<23328, 256, 0, stream>>>(regB);
  k_zhalo<20, 16, 256><<<8000, 256, 0, stream>>>(regC);

  // encoder
  k_conv<1, 16, 128, 64, 16, true, false, 0, true, 68>
      <<<dim3(4096, 1), 256, 0, stream>>>(x, w1, b1, regA);
  k_conv<16, 32, 64, 32, 16, true, true, 68, true, 36>
      <<<dim3(512, 2), 256, 0, stream>>>(regA, w2, b2, regB);
  k_conv<32, 64, 32, 16, 4, false, true, 36, false, 16>
      <<<dim3(64, 16), 256, 0, stream>>>(regB, w3, b3, ze);
  // vector quantization
  k_vq<<<4096, 256, 0, stream>>>(ze, cb, quant, regC);
  // decoder
  k_convt<64, 32, 16, 2, 1, 20, true, 36>
      <<<dim3(64, 16), 256, 0, stream>>>(regC, dw1, db1, regB);
  k_convt<32, 16, 32, 4, 1, 36, true, 68>
      <<<dim3(512, 4), 256, 0, stream>>>(regB, dw2, db2, regA);
  k_convt<16, 1, 64, 1, 2, 68, false, 0>
      <<<dim3(4096, 1), 256, 0, stream>>>(regA, dw3, db3, xhat);
}